// Round 8
// baseline (7807.281 us; speedup 1.0000x reference)
//
#include <hip/hip_runtime.h>

#define HB 65536  // 128*512 elements per [b][512] state plane
#define NBLK 256

typedef unsigned short u16;
typedef unsigned long long u64;
typedef __attribute__((ext_vector_type(8))) short bf16x8;
typedef __attribute__((ext_vector_type(8))) _Float16 f16x8;
typedef __attribute__((ext_vector_type(4))) float f32x4;
typedef __attribute__((ext_vector_type(2))) unsigned long long u64x2;
typedef __attribute__((ext_vector_type(8))) short s16x8;

#define MFMA_F16(a, b, c) __builtin_amdgcn_mfma_f32_16x16x32_f16(a, b, c, 0, 0, 0)
#define MFMA_BF16(a, b, c) __builtin_amdgcn_mfma_f32_16x16x32_bf16(a, b, c, 0, 0, 0)

__device__ __forceinline__ float fsig(float x) { return 1.f / (1.f + __expf(-x)); }
__device__ __forceinline__ float ftanh(float x) {
  float e = __expf(2.f * x);
  return 1.f - 2.f / (e + 1.f);
}
__device__ __forceinline__ u16 f2bf(float f) {
  unsigned u = __builtin_bit_cast(unsigned, f);
  return (u16)((u + 0x7FFFu + ((u >> 16) & 1)) >> 16);
}
__device__ __forceinline__ float bf2f(u16 h) {
  unsigned u = ((unsigned)h) << 16;
  return __builtin_bit_cast(float, u);
}
__device__ __forceinline__ u16 f2h(float f) {
  _Float16 h = (_Float16)f;
  return __builtin_bit_cast(u16, h);
}

// ---- coherence-point atomics (bypass non-coherent caches; no fences needed) ----
__device__ __forceinline__ u64 at_ld64(const void* p) {
  return __hip_atomic_load((const u64*)p, __ATOMIC_RELAXED, __HIP_MEMORY_SCOPE_AGENT);
}
__device__ __forceinline__ void at_st64(void* p, u64 v) {
  __hip_atomic_store((u64*)p, v, __ATOMIC_RELAXED, __HIP_MEMORY_SCOPE_AGENT);
}
__device__ __forceinline__ unsigned at_ld32(const void* p) {
  return __hip_atomic_load((const unsigned*)p, __ATOMIC_RELAXED, __HIP_MEMORY_SCOPE_AGENT);
}
__device__ __forceinline__ u64 pk4(u16 a, u16 b, u16 c, u16 d) {
  return (u64)a | ((u64)b << 16) | ((u64)c << 32) | ((u64)d << 48);
}
__device__ __forceinline__ u64 pkf2(float a, float b) {
  return (u64)__builtin_bit_cast(unsigned, a) | ((u64)__builtin_bit_cast(unsigned, b) << 32);
}

// ---- pack weights [2048][K] fp32 -> fragment-major hi/lo ----
template <bool F16>
__global__ void pack_w(const float* __restrict__ W, u16* __restrict__ dst, int K) {
  int NKT = K >> 5;
  long gid = (long)blockIdx.x * 256 + threadIdx.x;
  long total = (long)128 * NKT * 64;
  if (gid >= total) return;
  int lane = gid & 63;
  int kt = (gid >> 6) % NKT;
  int rt = (gid >> 6) / NKT;
  int r = lane & 15;
  int grow = (r >> 2) * 512 + rt * 4 + (r & 3);
  int k0 = kt * 32 + (lane >> 4) * 8;
  long base = ((long)(rt * NKT + kt) * 2) * 512 + lane * 8;
#pragma unroll
  for (int e = 0; e < 8; ++e) {
    float w = W[(long)grow * K + k0 + e];
    u16 hi, lo;
    if (F16) {
      _Float16 h = (_Float16)w;
      hi = __builtin_bit_cast(u16, h);
      _Float16 l2 = (_Float16)(w - (float)h);
      lo = __builtin_bit_cast(u16, l2);
    } else {
      hi = f2bf(w);
      lo = f2bf(w - bf2f(hi));
    }
    dst[base + e] = hi;
    dst[base + 512 + e] = lo;
  }
}

__global__ void pack_x(const float* __restrict__ x, u16* __restrict__ xp) {
  long gid = (long)blockIdx.x * 256 + threadIdx.x;
  if (gid >= 128L * 256 * 64) return;
  int k = gid & 63;
  long bt = gid >> 6;
  int t = bt & 255;
  int b = bt >> 8;
  xp[((long)t * 128 + b) * 64 + k] = f2h(x[((long)b * 256 + t) * 64 + k]);
}

__global__ void pack_bias(const float* __restrict__ b0f, const float* __restrict__ b0b,
                          const float* __restrict__ b1f, const float* __restrict__ b1b,
                          float* __restrict__ bp) {
  int gid = blockIdx.x * 256 + threadIdx.x;
  if (gid >= 8192) return;
  int src = gid >> 11;
  int idx = gid & 2047;
  int rt = idx >> 4, rr = idx & 15;
  int grow = (rr >> 2) * 512 + rt * 4 + (rr & 3);
  const float* B = (src == 0) ? b0f : (src == 1) ? b0b : (src == 2) ? b1f : b1b;
  bp[gid] = B[grow];
}

// barrier counter indices
#define C_L0 0        // [s 256][grp 8] target 32
#define C_TRANS 2048  // target 256
#define C_L1 2049     // [s 255][grp 4] target 64 (steps 0..254)
#define C_FIN 3072    // target 256

// ---- persistent kernel ----
__global__ __launch_bounds__(512, 1) void lstm_persist(
    const u16* __restrict__ xpack, u16* __restrict__ h0arch,
    const u16* __restrict__ wih0f_p, const u16* __restrict__ wih0b_p,
    const u16* __restrict__ whh0f_p, const u16* __restrict__ whh0b_p,
    const u16* __restrict__ wih1f_p, const u16* __restrict__ whh1f_p,
    const u16* __restrict__ wih1b_p, const u16* __restrict__ whh1b_p,
    const float* __restrict__ biasP,
    u16* __restrict__ hl0, u16* __restrict__ hl1,
    float* __restrict__ h1bf32,
    const float* __restrict__ fcw, const float* __restrict__ fcb,
    float* __restrict__ out, unsigned* __restrict__ cnt) {
  const int bid = blockIdx.x;
  const int xcd = bid & 7, slot = bid >> 3;
  const int tid = threadIdx.x;
  const int wid = tid >> 6, l = tid & 63;
  const int c = l & 15, q = l >> 4;

  __shared__ __align__(16) char smem[65536];   // h staging: [hi 32K | lo 32K]
  __shared__ __align__(16) f32x4 shacc[512];   // separate 8 KB reduce buffer

  const f32x4 fz = {0.f, 0.f, 0.f, 0.f};

  auto arrive = [&](int idx) {
    asm volatile("s_waitcnt vmcnt(0)" ::: "memory");  // own sc1 stores at coherence point
    __syncthreads();
    if (tid == 0)
      __hip_atomic_fetch_add(cnt + idx, 1u, __ATOMIC_RELAXED, __HIP_MEMORY_SCOPE_AGENT);
  };
  auto waitbar = [&](int idx, unsigned tgt) {
    if (tid == 0) {
      while (at_ld32(cnt + idx) < tgt) __builtin_amdgcn_s_sleep(1);
    }
    __syncthreads();
  };

  // ================= Phase L0: 256 steps, both dirs, 8 independent groups =================
  {
    const int d = slot >> 4;
    const int bg = (slot >> 2) & 3;
    const int grp = d * 4 + bg;
    const int ug = xcd * 4 + (slot & 3);
    const int rowt = ug * 4 + (wid >> 1);
    const int btl = wid & 1;
    const int b0 = bg * 32 + btl * 16;
    const int bl = btl * 16 + c;
    const int blsw = (bl & 7) << 4;
    const u16* wxp = d ? wih0b_p : wih0f_p;
    const u16* whp = d ? whh0b_p : whh0f_p;
    const float* bp = biasP + ((long)d * 128 + rowt) * 16 + q * 4;
    float c_reg[4] = {0.f, 0.f, 0.f, 0.f};
    for (int s = 0; s < 256; ++s) {
      const int t = d ? 255 - s : s;
      const int par = s & 1;
      u64x2 v[8];
      if (s) {
        waitbar(C_L0 + (s - 1) * 8 + grp, 32);
        const u16* hp_hi = hl0 + ((long)(par * 2 + d) * 2) * HB;
        const u16* hp_lo = hp_hi + HB;
#pragma unroll
        for (int i = 0; i < 8; ++i) {
          int m = tid + (i << 9);
          int pl = m >> 11, r = m & 2047;
          int b = r >> 6, k16 = r & 63;
          const u16* src = (pl ? hp_lo : hp_hi) + (long)(bg * 32 + b) * 512 + k16 * 8;
          v[i].x = at_ld64(src);
          v[i].y = at_ld64(src + 4);
        }
      }
      // x-projection (independent of staged h; covers sc1 load latency)
      f32x4 a0 = fz, a1 = fz;
      {
        const u16* bbase = xpack + ((long)t * 128 + b0 + c) * 64 + q * 8;
#pragma unroll
        for (int kt = 0; kt < 2; ++kt) {
          const u16* a = wxp + ((long)(rowt * 2 + kt) * 2) * 512 + l * 8;
          f16x8 ahi = *(const f16x8*)a;
          f16x8 alo = *(const f16x8*)(a + 512);
          f16x8 bx = *(const f16x8*)(bbase + kt * 32);
          f32x4& t0 = kt ? a1 : a0;
          t0 = MFMA_F16(ahi, bx, t0);
          t0 = MFMA_F16(alo, bx, t0);
        }
      }
      if (s) {
#pragma unroll
        for (int i = 0; i < 8; ++i) {
          int m = tid + (i << 9);
          int pl = m >> 11, r = m & 2047;
          int b = r >> 6, k16 = r & 63;
          int dst = pl * 32768 + (((b << 10) | (k16 << 4)) ^ ((b & 7) << 4));
          *(u64x2*)(smem + dst) = v[i];
        }
        __syncthreads();
#pragma unroll
        for (int kt = 0; kt < 16; ++kt) {
          const u16* a = whp + ((long)(rowt * 16 + kt) * 2) * 512 + l * 8;
          bf16x8 ahi = *(const bf16x8*)a;
          bf16x8 alo = *(const bf16x8*)(a + 512);
          int base = ((bl << 10) | (kt << 6) | (q << 4)) ^ blsw;
          bf16x8 bhi = *(const bf16x8*)(smem + base);
          bf16x8 blo = *(const bf16x8*)(smem + 32768 + base);
          f32x4& t0 = (kt & 1) ? a1 : a0;
          t0 = MFMA_BF16(ahi, bhi, t0);
          t0 = MFMA_BF16(alo, bhi, t0);
          t0 = MFMA_BF16(ahi, blo, t0);
        }
      }
      f32x4 acc = a0 + a1;
      float pre[4];
#pragma unroll
      for (int i = 0; i < 4; ++i) pre[i] = acc[i] + bp[i];
      const int par_w = par ^ 1;
      u16* hn_hi = hl0 + ((long)(par_w * 2 + d) * 2) * HB;
      u16* hn_lo = hn_hi + HB;
      const int b = b0 + c;
      u16 pbh[4], pbl[4], pf[4];
#pragma unroll
      for (int i = 0; i < 4; ++i) {
        float gI = __shfl(pre[i], c);
        float gF = __shfl(pre[i], c + 16);
        float gG = __shfl(pre[i], c + 32);
        float gO = __shfl(pre[i], c + 48);
        float cn = fsig(gF) * c_reg[i] + fsig(gI) * ftanh(gG);
        c_reg[i] = cn;
        float hv = fsig(gO) * ftanh(cn);
        u16 hh = f2bf(hv);
        pbh[i] = hh;
        pbl[i] = f2bf(hv - bf2f(hh));
        pf[i] = f2h(hv);
      }
      if (q == 0) {
        if (s < 255) {
          at_st64(hn_hi + (long)b * 512 + rowt * 4, pk4(pbh[0], pbh[1], pbh[2], pbh[3]));
          at_st64(hn_lo + (long)b * 512 + rowt * 4, pk4(pbl[0], pbl[1], pbl[2], pbl[3]));
        }
        at_st64(h0arch + ((long)t * 128 + b) * 1024 + d * 512 + rowt * 4,
                pk4(pf[0], pf[1], pf[2], pf[3]));
      }
      arrive(s < 255 ? C_L0 + s * 8 + grp : C_TRANS);
    }
  }
  waitbar(C_TRANS, NBLK);
  __threadfence();  // one-time L2 invalidate: plain h0arch reads below see fresh data
  __syncthreads();

  // L1 partition constants
  const int ug1 = xcd * 8 + (slot & 7);
  const int bg1 = slot >> 3;
  const int rl1 = (wid >> 1) & 1;
  const int btl1 = wid & 1;
  const int kh = wid >> 2;
  const int rowt1 = ug1 * 2 + rl1;
  const int b01 = bg1 * 32 + btl1 * 16;
  const int bl1 = btl1 * 16 + c;
  const int blsw1 = (bl1 & 7) << 4;

  // ================= Phase L1B: single step t=255 (zero state); no barrier needed ====
  {
    f32x4 a0 = fz, a1 = fz;
    const u16* bbase = h0arch + (255L * 128 + b01 + c) * 1024 + q * 8;
#pragma unroll
    for (int kk = 0; kk < 16; ++kk) {
      int kt = kh * 16 + kk;
      const u16* a = wih1b_p + ((long)(rowt1 * 32 + kt) * 2) * 512 + l * 8;
      f16x8 ahi = *(const f16x8*)a;
      f16x8 alo = *(const f16x8*)(a + 512);
      f16x8 bx = *(const f16x8*)(bbase + kt * 32);
      f32x4& t0 = (kk & 1) ? a1 : a0;
      t0 = MFMA_F16(ahi, bx, t0);
      t0 = MFMA_F16(alo, bx, t0);
    }
    f32x4 acc = a0 + a1;
    shacc[wid * 64 + l] = acc;
    __syncthreads();
    if (wid < 4) {
      f32x4 tot = shacc[wid * 64 + l] + shacc[(wid + 4) * 64 + l];
      const float* bp1 = biasP + (3L * 128 + rowt1) * 16 + q * 4;
      float pre[4];
#pragma unroll
      for (int i = 0; i < 4; ++i) pre[i] = tot[i] + bp1[i];
      const int b = b01 + c;
      float hv[4];
#pragma unroll
      for (int i = 0; i < 4; ++i) {
        float gI = __shfl(pre[i], c);
        float gG = __shfl(pre[i], c + 32);
        float gO = __shfl(pre[i], c + 48);
        float cn = fsig(gI) * ftanh(gG);
        hv[i] = fsig(gO) * ftanh(cn);
      }
      if (q == 0) {
        at_st64((u16*)(h1bf32 + (long)b * 512 + rowt1 * 4), pkf2(hv[0], hv[1]));
        at_st64((u16*)(h1bf32 + (long)b * 512 + rowt1 * 4 + 2), pkf2(hv[2], hv[3]));
      }
    }
    __syncthreads();  // shacc reuse below
  }

  // ================= Phase L1F: 256 steps forward, 4 independent groups ==========
  {
    float c_reg[4] = {0.f, 0.f, 0.f, 0.f};
    for (int s = 0; s < 256; ++s) {
      const int par = s & 1;
      u64x2 v[8];
      if (s) {
        waitbar(C_L1 + (s - 1) * 4 + bg1, 64);
        const u16* hp_hi = hl1 + (long)(par * 2) * HB;
        const u16* hp_lo = hp_hi + HB;
#pragma unroll
        for (int i = 0; i < 8; ++i) {
          int m = tid + (i << 9);
          int pl = m >> 11, r = m & 2047;
          int b = r >> 6, k16 = r & 63;
          const u16* src = (pl ? hp_lo : hp_hi) + (long)(bg1 * 32 + b) * 512 + k16 * 8;
          v[i].x = at_ld64(src);
          v[i].y = at_ld64(src + 4);
        }
      }
      // h0 projection (2/3 of the work): independent, covers sc1 load latency
      f32x4 a0 = fz, a1 = fz;
      const u16* bbase = h0arch + ((long)s * 128 + b01 + c) * 1024 + q * 8;
#pragma unroll
      for (int kk = 0; kk < 16; ++kk) {
        int kt = kh * 16 + kk;
        const u16* a = wih1f_p + ((long)(rowt1 * 32 + kt) * 2) * 512 + l * 8;
        f16x8 ahi = *(const f16x8*)a;
        f16x8 alo = *(const f16x8*)(a + 512);
        f16x8 bx = *(const f16x8*)(bbase + kt * 32);
        f32x4& t0 = (kk & 1) ? a1 : a0;
        t0 = MFMA_F16(ahi, bx, t0);
        t0 = MFMA_F16(alo, bx, t0);
      }
      if (s) {
#pragma unroll
        for (int i = 0; i < 8; ++i) {
          int m = tid + (i << 9);
          int pl = m >> 11, r = m & 2047;
          int b = r >> 6, k16 = r & 63;
          int dst = pl * 32768 + (((b << 10) | (k16 << 4)) ^ ((b & 7) << 4));
          *(u64x2*)(smem + dst) = v[i];
        }
        __syncthreads();
#pragma unroll
        for (int kk = 0; kk < 8; ++kk) {
          int kt = kh * 8 + kk;
          const u16* a = whh1f_p + ((long)(rowt1 * 16 + kt) * 2) * 512 + l * 8;
          bf16x8 ahi = *(const bf16x8*)a;
          bf16x8 alo = *(const bf16x8*)(a + 512);
          int base = ((bl1 << 10) | (kt << 6) | (q << 4)) ^ blsw1;
          bf16x8 bhi = *(const bf16x8*)(smem + base);
          bf16x8 blo = *(const bf16x8*)(smem + 32768 + base);
          f32x4& t0 = (kk & 1) ? a1 : a0;
          t0 = MFMA_BF16(ahi, bhi, t0);
          t0 = MFMA_BF16(alo, bhi, t0);
          t0 = MFMA_BF16(ahi, blo, t0);
        }
      }
      f32x4 acc = a0 + a1;
      shacc[wid * 64 + l] = acc;
      __syncthreads();
      if (wid < 4) {
        f32x4 tot = shacc[wid * 64 + l] + shacc[(wid + 4) * 64 + l];
        const float* bp1 = biasP + (2L * 128 + rowt1) * 16 + q * 4;
        float pre[4];
#pragma unroll
        for (int i = 0; i < 4; ++i) pre[i] = tot[i] + bp1[i];
        const int par_w = par ^ 1;
        u16* hn_hi = hl1 + (long)(par_w * 2) * HB;
        u16* hn_lo = hn_hi + HB;
        const int b = b01 + c;
        u16 pbh[4], pbl[4];
#pragma unroll
        for (int i = 0; i < 4; ++i) {
          float gI = __shfl(pre[i], c);
          float gF = __shfl(pre[i], c + 16);
          float gG = __shfl(pre[i], c + 32);
          float gO = __shfl(pre[i], c + 48);
          float cn = fsig(gF) * c_reg[i] + fsig(gI) * ftanh(gG);
          c_reg[i] = cn;
          float hv = fsig(gO) * ftanh(cn);
          u16 hh = f2bf(hv);
          pbh[i] = hh;
          pbl[i] = f2bf(hv - bf2f(hh));
        }
        if (q == 0) {
          at_st64(hn_hi + (long)b * 512 + rowt1 * 4, pk4(pbh[0], pbh[1], pbh[2], pbh[3]));
          at_st64(hn_lo + (long)b * 512 + rowt1 * 4, pk4(pbl[0], pbl[1], pbl[2], pbl[3]));
        }
      }
      arrive(s < 255 ? C_L1 + s * 4 + bg1 : C_FIN);
    }
  }
  waitbar(C_FIN, NBLK);

  // ================= FC =================
  if (bid < 128 && wid == 0) {
    const int b = bid;
    const int j0 = l * 8;
    u64x2 vh, vl;
    vh.x = at_ld64(hl1 + (long)b * 512 + j0);
    vh.y = at_ld64(hl1 + (long)b * 512 + j0 + 4);
    vl.x = at_ld64(hl1 + HB + (long)b * 512 + j0);
    vl.y = at_ld64(hl1 + HB + (long)b * 512 + j0 + 4);
    s16x8 hhi = __builtin_bit_cast(s16x8, vh);
    s16x8 hlo = __builtin_bit_cast(s16x8, vl);
    float ssum = 0.f;
#pragma unroll
    for (int e = 0; e < 8; ++e) {
      int j = j0 + e;
      float hf = bf2f((u16)hhi[e]) + bf2f((u16)hlo[e]);
      unsigned hbu = at_ld32(h1bf32 + (long)b * 512 + j);
      ssum += hf * fcw[j] + __builtin_bit_cast(float, hbu) * fcw[512 + j];
    }
#pragma unroll
    for (int off = 32; off; off >>= 1) ssum += __shfl_down(ssum, off);
    if (l == 0) out[b] = ssum + fcb[0];
  }
}

extern "C" void kernel_launch(void* const* d_in, const int* in_sizes, int n_in,
                              void* d_out, int out_size, void* d_ws, size_t ws_size,
                              hipStream_t stream) {
  const float* x     = (const float*)d_in[0];
  const float* wih0f = (const float*)d_in[1];
  const float* whh0f = (const float*)d_in[2];
  const float* b0f   = (const float*)d_in[3];
  const float* wih0b = (const float*)d_in[4];
  const float* whh0b = (const float*)d_in[5];
  const float* b0b   = (const float*)d_in[6];
  const float* wih1f = (const float*)d_in[7];
  const float* whh1f = (const float*)d_in[8];
  const float* b1f   = (const float*)d_in[9];
  const float* wih1b = (const float*)d_in[10];
  const float* whh1b = (const float*)d_in[11];
  const float* b1b   = (const float*)d_in[12];
  const float* fcw   = (const float*)d_in[13];
  const float* fcb   = (const float*)d_in[14];
  float* out = (float*)d_out;

  char* p = (char*)d_ws;
  auto alloc = [&](size_t bytes) {
    char* r = p;
    p += (bytes + 255) & ~(size_t)255;
    return r;
  };
  u16* xpack   = (u16*)alloc(128L * 256 * 64 * 2);
  u16* h0arch  = (u16*)alloc(256L * 128 * 1024 * 2);
  u16* wih0f_p = (u16*)alloc(128L * 2 * 2 * 512 * 2);
  u16* wih0b_p = (u16*)alloc(128L * 2 * 2 * 512 * 2);
  u16* whh0f_p = (u16*)alloc(128L * 16 * 2 * 512 * 2);
  u16* whh0b_p = (u16*)alloc(128L * 16 * 2 * 512 * 2);
  u16* wih1f_p = (u16*)alloc(128L * 32 * 2 * 512 * 2);
  u16* whh1f_p = (u16*)alloc(128L * 16 * 2 * 512 * 2);
  u16* wih1b_p = (u16*)alloc(128L * 32 * 2 * 512 * 2);
  u16* whh1b_p = (u16*)alloc(128L * 16 * 2 * 512 * 2);
  float* biasP = (float*)alloc(8192 * 4);
  u16* hl0     = (u16*)alloc(2L * 2 * 2 * HB * 2);  // [par][dir][hl][HB]
  u16* hl1     = (u16*)alloc(2L * 2 * HB * 2);      // [par][hl][HB]
  float* h1bf32= (float*)alloc((long)HB * 4);
  unsigned* cnt = (unsigned*)alloc(3104 * 4);

  pack_w<true><<<64, 256, 0, stream>>>(wih0f, wih0f_p, 64);
  pack_w<true><<<64, 256, 0, stream>>>(wih0b, wih0b_p, 64);
  pack_w<false><<<512, 256, 0, stream>>>(whh0f, whh0f_p, 512);
  pack_w<false><<<512, 256, 0, stream>>>(whh0b, whh0b_p, 512);
  pack_w<true><<<1024, 256, 0, stream>>>(wih1f, wih1f_p, 1024);
  pack_w<false><<<512, 256, 0, stream>>>(whh1f, whh1f_p, 512);
  pack_w<true><<<1024, 256, 0, stream>>>(wih1b, wih1b_p, 1024);
  pack_w<false><<<512, 256, 0, stream>>>(whh1b, whh1b_p, 512);
  pack_x<<<8192, 256, 0, stream>>>(x, xpack);
  pack_bias<<<32, 256, 0, stream>>>(b0f, b0b, b1f, b1b, biasP);

  (void)hipMemsetAsync(cnt, 0, 3104 * 4, stream);

  lstm_persist<<<NBLK, 512, 0, stream>>>(
      xpack, h0arch,
      wih0f_p, wih0b_p, whh0f_p, whh0b_p,
      wih1f_p, whh1f_p, wih1b_p, whh1b_p,
      biasP, hl0, hl1, h1bf32,
      fcw, fcb, out, cnt);
}

// Round 9
// 4136.595 us; speedup vs baseline: 1.8874x; 1.8874x over previous
//
#include <hip/hip_runtime.h>

#define HB 65536  // 128*512 elements per [b][512] state plane
#define NBLK 256

typedef unsigned short u16;
typedef unsigned long long u64;
typedef __attribute__((ext_vector_type(8))) short bf16x8;
typedef __attribute__((ext_vector_type(8))) _Float16 f16x8;
typedef __attribute__((ext_vector_type(4))) float f32x4;
typedef __attribute__((ext_vector_type(2))) unsigned long long u64x2;
typedef __attribute__((ext_vector_type(8))) short s16x8;

#define MFMA_F16(a, b, c) __builtin_amdgcn_mfma_f32_16x16x32_f16(a, b, c, 0, 0, 0)
#define MFMA_BF16(a, b, c) __builtin_amdgcn_mfma_f32_16x16x32_bf16(a, b, c, 0, 0, 0)

__device__ __forceinline__ float fsig(float x) { return 1.f / (1.f + __expf(-x)); }
__device__ __forceinline__ float ftanh(float x) {
  float e = __expf(2.f * x);
  return 1.f - 2.f / (e + 1.f);
}
__device__ __forceinline__ u16 f2bf(float f) {
  unsigned u = __builtin_bit_cast(unsigned, f);
  return (u16)((u + 0x7FFFu + ((u >> 16) & 1)) >> 16);
}
__device__ __forceinline__ float bf2f(u16 h) {
  unsigned u = ((unsigned)h) << 16;
  return __builtin_bit_cast(float, u);
}
__device__ __forceinline__ u16 f2h(float f) {
  _Float16 h = (_Float16)f;
  return __builtin_bit_cast(u16, h);
}

// ---- coherence-point atomics (bypass non-coherent caches; no fences needed) ----
__device__ __forceinline__ u64 at_ld64(const void* p) {
  return __hip_atomic_load((const u64*)p, __ATOMIC_RELAXED, __HIP_MEMORY_SCOPE_AGENT);
}
__device__ __forceinline__ void at_st64(void* p, u64 v) {
  __hip_atomic_store((u64*)p, v, __ATOMIC_RELAXED, __HIP_MEMORY_SCOPE_AGENT);
}
__device__ __forceinline__ unsigned at_ld32(const void* p) {
  return __hip_atomic_load((const unsigned*)p, __ATOMIC_RELAXED, __HIP_MEMORY_SCOPE_AGENT);
}
__device__ __forceinline__ void at_st32(void* p, unsigned v) {
  __hip_atomic_store((unsigned*)p, v, __ATOMIC_RELAXED, __HIP_MEMORY_SCOPE_AGENT);
}
__device__ __forceinline__ u64 pk4(u16 a, u16 b, u16 c, u16 d) {
  return (u64)a | ((u64)b << 16) | ((u64)c << 32) | ((u64)d << 48);
}
__device__ __forceinline__ u64 pkf2(float a, float b) {
  return (u64)__builtin_bit_cast(unsigned, a) | ((u64)__builtin_bit_cast(unsigned, b) << 32);
}

// ---- pack weights [2048][K] fp32 -> fragment-major hi/lo ----
template <bool F16>
__global__ void pack_w(const float* __restrict__ W, u16* __restrict__ dst, int K) {
  int NKT = K >> 5;
  long gid = (long)blockIdx.x * 256 + threadIdx.x;
  long total = (long)128 * NKT * 64;
  if (gid >= total) return;
  int lane = gid & 63;
  int kt = (gid >> 6) % NKT;
  int rt = (gid >> 6) / NKT;
  int r = lane & 15;
  int grow = (r >> 2) * 512 + rt * 4 + (r & 3);
  int k0 = kt * 32 + (lane >> 4) * 8;
  long base = ((long)(rt * NKT + kt) * 2) * 512 + lane * 8;
#pragma unroll
  for (int e = 0; e < 8; ++e) {
    float w = W[(long)grow * K + k0 + e];
    u16 hi, lo;
    if (F16) {
      _Float16 h = (_Float16)w;
      hi = __builtin_bit_cast(u16, h);
      _Float16 l2 = (_Float16)(w - (float)h);
      lo = __builtin_bit_cast(u16, l2);
    } else {
      hi = f2bf(w);
      lo = f2bf(w - bf2f(hi));
    }
    dst[base + e] = hi;
    dst[base + 512 + e] = lo;
  }
}

__global__ void pack_x(const float* __restrict__ x, u16* __restrict__ xp) {
  long gid = (long)blockIdx.x * 256 + threadIdx.x;
  if (gid >= 128L * 256 * 64) return;
  int k = gid & 63;
  long bt = gid >> 6;
  int t = bt & 255;
  int b = bt >> 8;
  xp[((long)t * 128 + b) * 64 + k] = f2h(x[((long)b * 256 + t) * 64 + k]);
}

__global__ void pack_bias(const float* __restrict__ b0f, const float* __restrict__ b0b,
                          const float* __restrict__ b1f, const float* __restrict__ b1b,
                          float* __restrict__ bp) {
  int gid = blockIdx.x * 256 + threadIdx.x;
  if (gid >= 8192) return;
  int src = gid >> 11;
  int idx = gid & 2047;
  int rt = idx >> 4, rr = idx & 15;
  int grow = (rr >> 2) * 512 + rt * 4 + (rr & 3);
  const float* B = (src == 0) ? b0f : (src == 1) ? b0b : (src == 2) ? b1f : b1b;
  bp[gid] = B[grow];
}

#define C_TRANS 0
#define C_FIN 64  // separate cache line

// ---- persistent kernel ----
__global__ __launch_bounds__(512, 1) void lstm_persist(
    const u16* __restrict__ xpack, u16* __restrict__ h0arch,
    const u16* __restrict__ wih0f_p, const u16* __restrict__ wih0b_p,
    const u16* __restrict__ whh0f_p, const u16* __restrict__ whh0b_p,
    const u16* __restrict__ wih1f_p, const u16* __restrict__ whh1f_p,
    const u16* __restrict__ wih1b_p, const u16* __restrict__ whh1b_p,
    const float* __restrict__ biasP,
    u16* __restrict__ hl0, u16* __restrict__ hl1,
    float* __restrict__ h1bf32,
    const float* __restrict__ fcw, const float* __restrict__ fcb,
    float* __restrict__ out,
    unsigned* __restrict__ flagsA, unsigned* __restrict__ flagsB,
    unsigned* __restrict__ cnt) {
  const int bid = blockIdx.x;
  const int xcd = bid & 7, slot = bid >> 3;
  const int tid = threadIdx.x;
  const int wid = tid >> 6, l = tid & 63;
  const int c = l & 15, q = l >> 4;

  __shared__ __align__(16) char smem[65536];   // h staging: [hi 32K | lo 32K]
  __shared__ __align__(16) f32x4 shacc[512];   // separate 8 KB reduce buffer

  const f32x4 fz = {0.f, 0.f, 0.f, 0.f};

  // RMW-free arrive: own padded flag line, plain sc1 store
  auto arriveflag = [&](unsigned* fl, unsigned gen) {
    asm volatile("s_waitcnt vmcnt(0)" ::: "memory");  // all my sc1 data stores at L3
    __syncthreads();                                   // all waves drained
    if (tid == 0) at_st32(fl + (long)bid * 64, gen);
  };
  // parallel-lane poll: lane i watches member i's flag (distinct 256B lines)
  auto waitflags = [&](const unsigned* fl, int base, int nmem, unsigned gen) {
    if (wid == 0) {
      unsigned f;
      do {
        f = (l < nmem) ? at_ld32(fl + (long)(base + l) * 64) : gen;
      } while (__ballot(f < gen));
    }
    __syncthreads();
  };
  auto arrivecnt = [&](int idx) {
    asm volatile("s_waitcnt vmcnt(0)" ::: "memory");
    __syncthreads();
    if (tid == 0)
      __hip_atomic_fetch_add(cnt + idx, 1u, __ATOMIC_RELAXED, __HIP_MEMORY_SCOPE_AGENT);
  };
  auto waitcnt_ = [&](int idx, unsigned tgt) {
    if (tid == 0) {
      while (at_ld32(cnt + idx) < tgt) __builtin_amdgcn_s_sleep(1);
    }
    __syncthreads();
  };

  // ================= Phase L0: 256 steps, both dirs, 8 independent groups =================
  {
    const int d = slot >> 4;
    const int bg = (slot >> 2) & 3;
    const int gbase = d * 128 + bg * 32;  // group = 32 contiguous bids
    const int ug = xcd * 4 + (slot & 3);
    const int rowt = ug * 4 + (wid >> 1);
    const int btl = wid & 1;
    const int b0 = bg * 32 + btl * 16;
    const int bl = btl * 16 + c;
    const int blsw = (bl & 7) << 4;
    const u16* wxp = d ? wih0b_p : wih0f_p;
    const u16* whp = d ? whh0b_p : whh0f_p;
    const float* bp = biasP + ((long)d * 128 + rowt) * 16 + q * 4;
    float c_reg[4] = {0.f, 0.f, 0.f, 0.f};
    for (int s = 0; s < 256; ++s) {
      const int t = d ? 255 - s : s;
      const int par = s & 1;
      // x-projection FIRST: overlaps other blocks' arrival + flag propagation
      f32x4 a0 = fz, a1 = fz;
      {
        const u16* bbase = xpack + ((long)t * 128 + b0 + c) * 64 + q * 8;
#pragma unroll
        for (int kt = 0; kt < 2; ++kt) {
          const u16* a = wxp + ((long)(rowt * 2 + kt) * 2) * 512 + l * 8;
          f16x8 ahi = *(const f16x8*)a;
          f16x8 alo = *(const f16x8*)(a + 512);
          f16x8 bx = *(const f16x8*)(bbase + kt * 32);
          f32x4& t0 = kt ? a1 : a0;
          t0 = MFMA_F16(ahi, bx, t0);
          t0 = MFMA_F16(alo, bx, t0);
        }
      }
      if (s) {
        waitflags(flagsA, gbase, 32, s);
        const u16* hp_hi = hl0 + ((long)(par * 2 + d) * 2) * HB;
        const u16* hp_lo = hp_hi + HB;
#pragma unroll
        for (int i = 0; i < 8; ++i) {
          int m = tid + (i << 9);
          int pl = m >> 11, r = m & 2047;
          int b = r >> 6, k16 = r & 63;
          const u16* src = (pl ? hp_lo : hp_hi) + (long)(bg * 32 + b) * 512 + k16 * 8;
          u64x2 v;
          v.x = at_ld64(src);
          v.y = at_ld64(src + 4);
          int dst = pl * 32768 + (((b << 10) | (k16 << 4)) ^ ((b & 7) << 4));
          *(u64x2*)(smem + dst) = v;
        }
        __syncthreads();
#pragma unroll
        for (int kt = 0; kt < 16; ++kt) {
          const u16* a = whp + ((long)(rowt * 16 + kt) * 2) * 512 + l * 8;
          bf16x8 ahi = *(const bf16x8*)a;
          bf16x8 alo = *(const bf16x8*)(a + 512);
          int base = ((bl << 10) | (kt << 6) | (q << 4)) ^ blsw;
          bf16x8 bhi = *(const bf16x8*)(smem + base);
          bf16x8 blo = *(const bf16x8*)(smem + 32768 + base);
          f32x4& t0 = (kt & 1) ? a1 : a0;
          t0 = MFMA_BF16(ahi, bhi, t0);
          t0 = MFMA_BF16(alo, bhi, t0);
          t0 = MFMA_BF16(ahi, blo, t0);
        }
        __syncthreads();  // done reading smem before next step overwrites
      }
      f32x4 acc = a0 + a1;
      float pre[4];
#pragma unroll
      for (int i = 0; i < 4; ++i) pre[i] = acc[i] + bp[i];
      const int par_w = par ^ 1;
      u16* hn_hi = hl0 + ((long)(par_w * 2 + d) * 2) * HB;
      u16* hn_lo = hn_hi + HB;
      const int b = b0 + c;
      u16 pbh[4], pbl[4], pf[4];
#pragma unroll
      for (int i = 0; i < 4; ++i) {
        float gI = __shfl(pre[i], c);
        float gF = __shfl(pre[i], c + 16);
        float gG = __shfl(pre[i], c + 32);
        float gO = __shfl(pre[i], c + 48);
        float cn = fsig(gF) * c_reg[i] + fsig(gI) * ftanh(gG);
        c_reg[i] = cn;
        float hv = fsig(gO) * ftanh(cn);
        u16 hh = f2bf(hv);
        pbh[i] = hh;
        pbl[i] = f2bf(hv - bf2f(hh));
        pf[i] = f2h(hv);
      }
      if (q == 0) {
        if (s < 255) {
          at_st64(hn_hi + (long)b * 512 + rowt * 4, pk4(pbh[0], pbh[1], pbh[2], pbh[3]));
          at_st64(hn_lo + (long)b * 512 + rowt * 4, pk4(pbl[0], pbl[1], pbl[2], pbl[3]));
        }
        at_st64(h0arch + ((long)t * 128 + b) * 1024 + d * 512 + rowt * 4,
                pk4(pf[0], pf[1], pf[2], pf[3]));
      }
      if (s < 255) arriveflag(flagsA, (unsigned)(s + 1));
      else arrivecnt(C_TRANS);
    }
  }
  waitcnt_(C_TRANS, NBLK);
  __threadfence();  // one-time L2 invalidate: plain h0arch reads below see fresh data
  __syncthreads();

  // L1 partition constants
  const int ug1 = xcd * 8 + (slot & 7);
  const int bg1 = slot >> 3;
  const int rl1 = (wid >> 1) & 1;
  const int btl1 = wid & 1;
  const int kh = wid >> 2;
  const int rowt1 = ug1 * 2 + rl1;
  const int b01 = bg1 * 32 + btl1 * 16;
  const int bl1 = btl1 * 16 + c;
  const int blsw1 = (bl1 & 7) << 4;

  // ================= Phase L1B: single step t=255 (zero state); no barrier needed ====
  {
    f32x4 a0 = fz, a1 = fz;
    const u16* bbase = h0arch + (255L * 128 + b01 + c) * 1024 + q * 8;
#pragma unroll
    for (int kk = 0; kk < 16; ++kk) {
      int kt = kh * 16 + kk;
      const u16* a = wih1b_p + ((long)(rowt1 * 32 + kt) * 2) * 512 + l * 8;
      f16x8 ahi = *(const f16x8*)a;
      f16x8 alo = *(const f16x8*)(a + 512);
      f16x8 bx = *(const f16x8*)(bbase + kt * 32);
      f32x4& t0 = (kk & 1) ? a1 : a0;
      t0 = MFMA_F16(ahi, bx, t0);
      t0 = MFMA_F16(alo, bx, t0);
    }
    f32x4 acc = a0 + a1;
    shacc[wid * 64 + l] = acc;
    __syncthreads();
    if (wid < 4) {
      f32x4 tot = shacc[wid * 64 + l] + shacc[(wid + 4) * 64 + l];
      const float* bp1 = biasP + (3L * 128 + rowt1) * 16 + q * 4;
      float pre[4];
#pragma unroll
      for (int i = 0; i < 4; ++i) pre[i] = tot[i] + bp1[i];
      const int b = b01 + c;
      float hv[4];
#pragma unroll
      for (int i = 0; i < 4; ++i) {
        float gI = __shfl(pre[i], c);
        float gG = __shfl(pre[i], c + 32);
        float gO = __shfl(pre[i], c + 48);
        float cn = fsig(gI) * ftanh(gG);
        hv[i] = fsig(gO) * ftanh(cn);
      }
      if (q == 0) {
        at_st64((u16*)(h1bf32 + (long)b * 512 + rowt1 * 4), pkf2(hv[0], hv[1]));
        at_st64((u16*)(h1bf32 + (long)b * 512 + rowt1 * 4 + 2), pkf2(hv[2], hv[3]));
      }
    }
    __syncthreads();  // shacc reuse below
  }

  // ================= Phase L1F: 256 steps forward, 4 independent groups ==========
  {
    const int g1base = bg1 * 64;  // group = 64 contiguous bids
    float c_reg[4] = {0.f, 0.f, 0.f, 0.f};
    for (int s = 0; s < 256; ++s) {
      const int par = s & 1;
      // h0 projection FIRST (2/3 of work): overlaps arrival + propagation
      f32x4 a0 = fz, a1 = fz;
      const u16* bbase = h0arch + ((long)s * 128 + b01 + c) * 1024 + q * 8;
#pragma unroll
      for (int kk = 0; kk < 16; ++kk) {
        int kt = kh * 16 + kk;
        const u16* a = wih1f_p + ((long)(rowt1 * 32 + kt) * 2) * 512 + l * 8;
        f16x8 ahi = *(const f16x8*)a;
        f16x8 alo = *(const f16x8*)(a + 512);
        f16x8 bx = *(const f16x8*)(bbase + kt * 32);
        f32x4& t0 = (kk & 1) ? a1 : a0;
        t0 = MFMA_F16(ahi, bx, t0);
        t0 = MFMA_F16(alo, bx, t0);
      }
      if (s) {
        waitflags(flagsB, g1base, 64, s);
        const u16* hp_hi = hl1 + (long)(par * 2) * HB;
        const u16* hp_lo = hp_hi + HB;
#pragma unroll
        for (int i = 0; i < 8; ++i) {
          int m = tid + (i << 9);
          int pl = m >> 11, r = m & 2047;
          int b = r >> 6, k16 = r & 63;
          const u16* src = (pl ? hp_lo : hp_hi) + (long)(bg1 * 32 + b) * 512 + k16 * 8;
          u64x2 v;
          v.x = at_ld64(src);
          v.y = at_ld64(src + 4);
          int dst = pl * 32768 + (((b << 10) | (k16 << 4)) ^ ((b & 7) << 4));
          *(u64x2*)(smem + dst) = v;
        }
        __syncthreads();
#pragma unroll
        for (int kk = 0; kk < 8; ++kk) {
          int kt = kh * 8 + kk;
          const u16* a = whh1f_p + ((long)(rowt1 * 16 + kt) * 2) * 512 + l * 8;
          bf16x8 ahi = *(const bf16x8*)a;
          bf16x8 alo = *(const bf16x8*)(a + 512);
          int base = ((bl1 << 10) | (kt << 6) | (q << 4)) ^ blsw1;
          bf16x8 bhi = *(const bf16x8*)(smem + base);
          bf16x8 blo = *(const bf16x8*)(smem + 32768 + base);
          f32x4& t0 = (kk & 1) ? a1 : a0;
          t0 = MFMA_BF16(ahi, bhi, t0);
          t0 = MFMA_BF16(alo, bhi, t0);
          t0 = MFMA_BF16(ahi, blo, t0);
        }
        __syncthreads();  // done reading smem before next step overwrites
      }
      f32x4 acc = a0 + a1;
      shacc[wid * 64 + l] = acc;
      __syncthreads();
      if (wid < 4) {
        f32x4 tot = shacc[wid * 64 + l] + shacc[(wid + 4) * 64 + l];
        const float* bp1 = biasP + (2L * 128 + rowt1) * 16 + q * 4;
        float pre[4];
#pragma unroll
        for (int i = 0; i < 4; ++i) pre[i] = tot[i] + bp1[i];
        const int par_w = par ^ 1;
        u16* hn_hi = hl1 + (long)(par_w * 2) * HB;
        u16* hn_lo = hn_hi + HB;
        const int b = b01 + c;
        u16 pbh[4], pbl[4];
#pragma unroll
        for (int i = 0; i < 4; ++i) {
          float gI = __shfl(pre[i], c);
          float gF = __shfl(pre[i], c + 16);
          float gG = __shfl(pre[i], c + 32);
          float gO = __shfl(pre[i], c + 48);
          float cn = fsig(gF) * c_reg[i] + fsig(gI) * ftanh(gG);
          c_reg[i] = cn;
          float hv = fsig(gO) * ftanh(cn);
          u16 hh = f2bf(hv);
          pbh[i] = hh;
          pbl[i] = f2bf(hv - bf2f(hh));
        }
        if (q == 0 && s < 255) {
          at_st64(hn_hi + (long)b * 512 + rowt1 * 4, pk4(pbh[0], pbh[1], pbh[2], pbh[3]));
          at_st64(hn_lo + (long)b * 512 + rowt1 * 4, pk4(pbl[0], pbl[1], pbl[2], pbl[3]));
        }
        if (q == 0 && s == 255) {  // final h -> dedicated final buffer (parity 0 plane)
          u16* hf_hi = hl1;
          u16* hf_lo = hl1 + HB;
          at_st64(hf_hi + (long)b * 512 + rowt1 * 4, pk4(pbh[0], pbh[1], pbh[2], pbh[3]));
          at_st64(hf_lo + (long)b * 512 + rowt1 * 4, pk4(pbl[0], pbl[1], pbl[2], pbl[3]));
        }
      }
      if (s < 255) arriveflag(flagsB, (unsigned)(s + 1));
      else arrivecnt(C_FIN);
    }
  }
  waitcnt_(C_FIN, NBLK);

  // ================= FC =================
  if (bid < 128 && wid == 0) {
    const int b = bid;
    const int j0 = l * 8;
    u64x2 vh, vl;
    vh.x = at_ld64(hl1 + (long)b * 512 + j0);
    vh.y = at_ld64(hl1 + (long)b * 512 + j0 + 4);
    vl.x = at_ld64(hl1 + HB + (long)b * 512 + j0);
    vl.y = at_ld64(hl1 + HB + (long)b * 512 + j0 + 4);
    s16x8 hhi = __builtin_bit_cast(s16x8, vh);
    s16x8 hlo = __builtin_bit_cast(s16x8, vl);
    float ssum = 0.f;
#pragma unroll
    for (int e = 0; e < 8; ++e) {
      int j = j0 + e;
      float hf = bf2f((u16)hhi[e]) + bf2f((u16)hlo[e]);
      unsigned hbu = at_ld32(h1bf32 + (long)b * 512 + j);
      ssum += hf * fcw[j] + __builtin_bit_cast(float, hbu) * fcw[512 + j];
    }
#pragma unroll
    for (int off = 32; off; off >>= 1) ssum += __shfl_down(ssum, off);
    if (l == 0) out[b] = ssum + fcb[0];
  }
}

extern "C" void kernel_launch(void* const* d_in, const int* in_sizes, int n_in,
                              void* d_out, int out_size, void* d_ws, size_t ws_size,
                              hipStream_t stream) {
  const float* x     = (const float*)d_in[0];
  const float* wih0f = (const float*)d_in[1];
  const float* whh0f = (const float*)d_in[2];
  const float* b0f   = (const float*)d_in[3];
  const float* wih0b = (const float*)d_in[4];
  const float* whh0b = (const float*)d_in[5];
  const float* b0b   = (const float*)d_in[6];
  const float* wih1f = (const float*)d_in[7];
  const float* whh1f = (const float*)d_in[8];
  const float* b1f   = (const float*)d_in[9];
  const float* wih1b = (const float*)d_in[10];
  const float* whh1b = (const float*)d_in[11];
  const float* b1b   = (const float*)d_in[12];
  const float* fcw   = (const float*)d_in[13];
  const float* fcb   = (const float*)d_in[14];
  float* out = (float*)d_out;

  char* p = (char*)d_ws;
  auto alloc = [&](size_t bytes) {
    char* r = p;
    p += (bytes + 255) & ~(size_t)255;
    return r;
  };
  u16* xpack   = (u16*)alloc(128L * 256 * 64 * 2);
  u16* h0arch  = (u16*)alloc(256L * 128 * 1024 * 2);
  u16* wih0f_p = (u16*)alloc(128L * 2 * 2 * 512 * 2);
  u16* wih0b_p = (u16*)alloc(128L * 2 * 2 * 512 * 2);
  u16* whh0f_p = (u16*)alloc(128L * 16 * 2 * 512 * 2);
  u16* whh0b_p = (u16*)alloc(128L * 16 * 2 * 512 * 2);
  u16* wih1f_p = (u16*)alloc(128L * 32 * 2 * 512 * 2);
  u16* whh1f_p = (u16*)alloc(128L * 16 * 2 * 512 * 2);
  u16* wih1b_p = (u16*)alloc(128L * 32 * 2 * 512 * 2);
  u16* whh1b_p = (u16*)alloc(128L * 16 * 2 * 512 * 2);
  float* biasP = (float*)alloc(8192 * 4);
  u16* hl0     = (u16*)alloc(2L * 2 * 2 * HB * 2);  // [par][dir][hl][HB]
  u16* hl1     = (u16*)alloc(2L * 2 * HB * 2);      // [par][hl][HB]
  float* h1bf32= (float*)alloc((long)HB * 4);
  unsigned* flagsA = (unsigned*)alloc(256L * 64 * 4);  // 256B-padded per-block flags
  unsigned* flagsB = (unsigned*)alloc(256L * 64 * 4);
  unsigned* cnt    = (unsigned*)alloc(128 * 4);

  pack_w<true><<<64, 256, 0, stream>>>(wih0f, wih0f_p, 64);
  pack_w<true><<<64, 256, 0, stream>>>(wih0b, wih0b_p, 64);
  pack_w<false><<<512, 256, 0, stream>>>(whh0f, whh0f_p, 512);
  pack_w<false><<<512, 256, 0, stream>>>(whh0b, whh0b_p, 512);
  pack_w<true><<<1024, 256, 0, stream>>>(wih1f, wih1f_p, 1024);
  pack_w<false><<<512, 256, 0, stream>>>(whh1f, whh1f_p, 512);
  pack_w<true><<<1024, 256, 0, stream>>>(wih1b, wih1b_p, 1024);
  pack_w<false><<<512, 256, 0, stream>>>(whh1b, whh1b_p, 512);
  pack_x<<<8192, 256, 0, stream>>>(x, xpack);
  pack_bias<<<32, 256, 0, stream>>>(b0f, b0b, b1f, b1b, biasP);

  (void)hipMemsetAsync(flagsA, 0, 256L * 64 * 4, stream);
  (void)hipMemsetAsync(flagsB, 0, 256L * 64 * 4, stream);
  (void)hipMemsetAsync(cnt, 0, 128 * 4, stream);

  lstm_persist<<<NBLK, 512, 0, stream>>>(
      xpack, h0arch,
      wih0f_p, wih0b_p, whh0f_p, whh0b_p,
      wih1f_p, whh1f_p, wih1b_p, whh1b_p,
      biasP, hl0, hl1, h1bf32,
      fcw, fcb, out, flagsA, flagsB, cnt);
}